// Round 12
// baseline (3546.699 us; speedup 1.0000x reference)
//
#include <hip/hip_runtime.h>
#include <hip/hip_bf16.h>

// ---------------------------------------------------------------------------
// RSSM scan on MI355X — round 12: r/u gate weights REGISTER-RESIDENT (fp8,
// 64 VGPR, asm-loaded + pinned -> non-rematerializable), n/q1h/eb/Wz streamed.
// 64 blocks x 1024 thr (16 waves), RPB=16. Numerics BIT-IDENTICAL to r11
// (absmax 0.1296 < 0.1319): same dtypes, same accumulate order.
// Wq1w moved to LDS (64KB; total 141KB). Stream ~300KB/CU/step (was 560).
// Ledger (consume-then-issue, FIFO-audited, never drains, min outstanding 6):
//   boot: obs nz Wz K0-3 (12); VMW(10); st4 -> 14
//   A: VMW(12)[Wz] | B: 10,10,10,10 (K0-3, issue K4-7), 6 (+db0-3),
//      8 (+db4-7), 10, 8 (+eb,obs',nz')
//   D: VMW(10),VMW(6)[db]; issue Wz'+K0-3' | E: VMW(12)[eb] | F: VMW(10)+st4
// Frag addr: bf16 shorts F[kt*512+l*8+j]; fp8 bytes F8[kt*512+l*8+j].
// ---------------------------------------------------------------------------

#define B_   1024
#define L_   256
#define WD_  128
#define AD_  32
#define DD_  256
#define SD_  64
#define HD_  256
#define NA_  17
#define OUT_ 576

typedef __attribute__((ext_vector_type(8))) short bf16x8;
typedef __attribute__((ext_vector_type(4))) float f32x4;
typedef __attribute__((ext_vector_type(2))) float f32x2;
typedef __attribute__((ext_vector_type(2))) unsigned u32x2;
typedef long long fp8x8;

// bf16 packed weights (shorts)
#define OFF_WZ   0         // 64 x 256
#define OFF_WQ1W 16384     // 128 x 256 (-> LDS)
#define OFF_WQ2  49152     // 256 x 128
#define OFF_WP1  81920     // 256 x 256
#define OFF_WP2  147456    // 256 x 128
#define PK_TOTAL 180224
#define OFF_ACTP_BYTES (PK_TOTAL * 2)
#define OFF_DSCR_BYTES (OFF_ACTP_BYTES + 32768)
#define OFF_W8_BYTES   (OFF_DSCR_BYTES + 65536)
// w8 (fp8): ih_r | ih_u | ih_n | hh_r | hh_u | hh_n | q1h  (7 x 64KB)
#define W8_IHR 0
#define W8_IHU 65536
#define W8_IHN 131072
#define W8_HHR 196608
#define W8_HHU 262144
#define W8_HHN 327680
#define W8_Q1H 393216

__device__ __forceinline__ short f2bf(float f) {
    union { float f; unsigned u; } v; v.f = f;
    unsigned r = (v.u + 0x7fffu + ((v.u >> 16) & 1u)) >> 16;  // RNE
    return (short)r;
}
__device__ __forceinline__ unsigned cvtpk(float a, float b) {
    unsigned r;
    asm("v_cvt_pk_bf16_f32 %0, %1, %2" : "=v"(r) : "v"(a), "v"(b));
    return r;
}
__device__ __forceinline__ int pk4fp8(float a, float b, float c, float d) {
    int r = __builtin_amdgcn_cvt_pk_fp8_f32(a, b, 0, false);
    r = __builtin_amdgcn_cvt_pk_fp8_f32(c, d, r, true);
    return r;
}

__device__ __forceinline__ f32x4 mfma16(bf16x8 a, bf16x8 b, f32x4 c) {
    return __builtin_amdgcn_mfma_f32_16x16x32_bf16(a, b, c, 0, 0, 0);
}
__device__ __forceinline__ f32x4 mfma8(fp8x8 a, fp8x8 b, f32x4 c) {
    return __builtin_amdgcn_mfma_f32_16x16x32_fp8_fp8(a, b, c, 0, 0, 0);
}

__device__ __forceinline__ float sigmoidf_(float x) { return 1.f / (1.f + __expf(-x)); }
__device__ __forceinline__ float tanhf_(float x)    { return 2.f / (1.f + __expf(-2.f * x)) - 1.f; }
__device__ __forceinline__ float softplusf_(float x){ return (x > 20.f) ? x : __logf(1.f + __expf(x)); }

template<int IMM>
__device__ __forceinline__ bf16x8 gload(const short* sbase, unsigned voff) {
    bf16x8 d;
    if constexpr (IMM == 0) {
        asm volatile("global_load_dwordx4 %0, %1, %2" : "=v"(d) : "v"(voff), "s"(sbase));
    } else {
        asm volatile("global_load_dwordx4 %0, %1, %2 offset:%3"
                     : "=v"(d) : "v"(voff), "s"(sbase), "i"(IMM));
    }
    return d;
}
template<int IMM>
__device__ __forceinline__ fp8x8 gload8(const char* sbase, unsigned voff) {
    fp8x8 d;
    if constexpr (IMM == 0) {
        asm volatile("global_load_dwordx2 %0, %1, %2" : "=v"(d) : "v"(voff), "s"(sbase));
    } else {
        asm volatile("global_load_dwordx2 %0, %1, %2 offset:%3"
                     : "=v"(d) : "v"(voff), "s"(sbase), "i"(IMM));
    }
    return d;
}
__device__ __forceinline__ f32x2 gload2f(const float* sbase, unsigned voff) {
    f32x2 d;
    asm volatile("global_load_dwordx2 %0, %1, %2 nt" : "=v"(d) : "v"(voff), "s"(sbase));
    return d;
}
__device__ __forceinline__ float gload1f(const float* sbase, unsigned voff) {
    float d;
    asm volatile("global_load_dword %0, %1, %2 nt" : "=v"(d) : "v"(voff), "s"(sbase));
    return d;
}
__device__ __forceinline__ void gstore4f(float* sbase, unsigned voff, f32x4 v) {
    asm volatile("global_store_dwordx4 %0, %1, %2 nt" :: "v"(voff), "v"(v), "s"(sbase));
}
__device__ __forceinline__ void gstore1f(float* sbase, unsigned voff, float v) {
    asm volatile("global_store_dword %0, %1, %2 nt" :: "v"(voff), "v"(v), "s"(sbase));
}

#define VMW(N) do { asm volatile("s_waitcnt vmcnt(" #N ")" ::: "memory"); \
                    __builtin_amdgcn_sched_barrier(0); } while (0)
#define BAR() do { asm volatile("s_waitcnt lgkmcnt(0)" ::: "memory"); \
                   __builtin_amdgcn_s_barrier(); \
                   __builtin_amdgcn_sched_barrier(0); } while (0)

// ---------------------------------------------------------------------------
__global__ void pack_w_kernel(const float* __restrict__ W, short* __restrict__ dst,
                              int KT, int rowOff, int srcN, int total) {
    int tid = blockIdx.x * 256 + threadIdx.x;
    if (tid >= total) return;
    int j    = tid & 7;
    int lane = (tid >> 3) & 63;
    int kt   = (tid >> 9) % KT;
    int nt   = (tid >> 9) / KT;
    int k = kt * 32 + (lane >> 4) * 8 + j;
    int n = nt * 16 + (lane & 15);
    dst[tid] = f2bf(W[(size_t)(rowOff + k) * srcN + n]);
}

__global__ void pack_f8_kernel(const float* __restrict__ W, char* __restrict__ dst,
                               int KT, int rowOff, int colOff, int srcN, int total) {
    int tid = blockIdx.x * 256 + threadIdx.x;
    if (tid >= total) return;
    int j    = tid & 7;
    int lane = (tid >> 3) & 63;
    int kt   = (tid >> 9) % KT;
    int nt   = (tid >> 9) / KT;
    int k = kt * 32 + (lane >> 4) * 8 + j;
    int n = colOff + nt * 16 + (lane & 15);
    float v = W[(size_t)(rowOff + k) * srcN + n];
    int p = __builtin_amdgcn_cvt_pk_fp8_f32(v, 0.f, 0, false);
    dst[tid] = (char)(p & 0xFF);
}

__global__ void act_proj_kernel(const float* __restrict__ emb, const float* __restrict__ w_in,
                                const float* __restrict__ b_in, float* __restrict__ actp) {
    int c = threadIdx.x;
    int a = blockIdx.x;
    float s = b_in[c];
    for (int i = 0; i < AD_; ++i) s += emb[a * AD_ + i] * w_in[(SD_ + i) * HD_ + c];
    actp[a * HD_ + c] = s;
}

// ---------------------------------------------------------------------------
#define RPB 16
#define NTH 1024

struct NB { fp8x8 ni, nh; };   // 4 VGPR (streamed n-gate pair)

template<int KT>
__device__ __forceinline__ void issueN(NB& b, const char* s8ni, const char* s8nh,
                                       unsigned voff8) {
    constexpr int IMM8 = KT * 512;
    b.ni = gload8<IMM8>(s8ni, voff8);
    b.nh = gload8<IMM8>(s8nh, voff8);
}

__launch_bounds__(NTH, 4)
__global__ void scan_kernel(const int* __restrict__ actions, const float* __restrict__ obs,
                            const float* __restrict__ noise,
                            const float* __restrict__ b_ih, const float* __restrict__ b_hh,
                            const float* __restrict__ g_ln, const float* __restrict__ beta_ln,
                            const float* __restrict__ b_q1, const float* __restrict__ b_q2,
                            const short* __restrict__ wpk, const char* __restrict__ w8,
                            const float* __restrict__ actp,
                            float* __restrict__ dscr, float* __restrict__ out) {
    __shared__ __align__(16) float ps_s [16][20];
    __shared__ __align__(16) float ps_ss[16][20];
    __shared__ __align__(16) float q2p[2][16][132];
    __shared__ __align__(16) char  xF8 [4096];
    __shared__ __align__(16) char  h8a [4096];
    __shared__ __align__(16) char  h8b [4096];
    __shared__ __align__(16) short q1F [4096];
    __shared__ __align__(16) short zF  [1024];
    __shared__ __align__(16) short obsF[2048];
    __shared__ __align__(16) short wq1w_l[32768];   // Wq1w bf16, all waves (64KB)
    __shared__ __align__(16) float bsr_l[256], bsu_l[256], bin_l[256], bhn_l[256];
    __shared__ __align__(16) float bq1_l[256], lng_l[256], lnb_l[256], bq2_l[128];
    __shared__ __align__(16) unsigned char act8_l[L_][16];
    __shared__ __align__(16) float actp_l[NA_][260];

    const int tid  = threadIdx.x;
    const int w    = tid >> 6;
    const int lane = tid & 63;
    const int lrow = lane & 15;
    const int lgrp = lane >> 4;
    const int row0 = blockIdx.x * RPB;
    const int c0   = w * 16 + lgrp * 4;
    const int foff = lane * 8;          // shorts
    const int b8off = lane * 8;         // bytes
    const int fwb  = (c0 >> 5) * 512 + (lrow + 16 * ((c0 >> 3) & 3)) * 8 + (c0 & 7);
    const f32x4 zero4 = {0.f, 0.f, 0.f, 0.f};

    const int wu = __builtin_amdgcn_readfirstlane(w);
    const unsigned voff16 = (unsigned)lane * 16u;
    const unsigned voff8  = (unsigned)lane * 8u;
    const short* sbwz = wpk + OFF_WZ + (wu * 2) * 512;
    const char* s8ri  = w8 + W8_IHR + (wu * 8) * 512;
    const char* s8ui  = w8 + W8_IHU + (wu * 8) * 512;
    const char* s8ni  = w8 + W8_IHN + (wu * 8) * 512;
    const char* s8rh  = w8 + W8_HHR + (wu * 8) * 512;
    const char* s8uh  = w8 + W8_HHU + (wu * 8) * 512;
    const char* s8nh  = w8 + W8_HHN + (wu * 8) * 512;
    const char* s8q1h = w8 + W8_Q1H + (wu * 8) * 512;
    const int khalf = wu >> 3;
    const short* sbq2 = wpk + OFF_WQ2 + ((wu & 7) * 8 + khalf * 4) * 512;

    // ---- RESIDENT r/u gate weights (fp8, 64 VGPR), asm-loaded once ----------
    fp8x8 Rih[8], Uih[8], Rhh[8], Uhh[8];
#define LOADRES(arr, base) \
    arr[0] = gload8<0>(base, voff8);    arr[1] = gload8<512>(base, voff8);  \
    arr[2] = gload8<1024>(base, voff8); arr[3] = gload8<1536>(base, voff8); \
    arr[4] = gload8<2048>(base, voff8); arr[5] = gload8<2560>(base, voff8); \
    arr[6] = gload8<3072>(base, voff8); arr[7] = gload8<3584>(base, voff8);
    LOADRES(Rih, s8ri)
    LOADRES(Uih, s8ui)
    LOADRES(Rhh, s8rh)
    LOADRES(Uhh, s8uh)
#undef LOADRES
    asm volatile("s_waitcnt vmcnt(0)" ::: "memory");
    asm volatile("" :: "v"(Rih[0]), "v"(Rih[1]), "v"(Rih[2]), "v"(Rih[3]),
                       "v"(Rih[4]), "v"(Rih[5]), "v"(Rih[6]), "v"(Rih[7]));
    asm volatile("" :: "v"(Uih[0]), "v"(Uih[1]), "v"(Uih[2]), "v"(Uih[3]),
                       "v"(Uih[4]), "v"(Uih[5]), "v"(Uih[6]), "v"(Uih[7]));
    asm volatile("" :: "v"(Rhh[0]), "v"(Rhh[1]), "v"(Rhh[2]), "v"(Rhh[3]),
                       "v"(Rhh[4]), "v"(Rhh[5]), "v"(Rhh[6]), "v"(Rhh[7]));
    asm volatile("" :: "v"(Uhh[0]), "v"(Uhh[1]), "v"(Uhh[2]), "v"(Uhh[3]),
                       "v"(Uhh[4]), "v"(Uhh[5]), "v"(Uhh[6]), "v"(Uhh[7]));

    // prologue: params/actions/actp/Wq1w -> LDS; zero state
    if (tid < 256) {
        bsr_l[tid] = b_ih[tid] + b_hh[tid];
        bsu_l[tid] = b_ih[256 + tid] + b_hh[256 + tid];
        bin_l[tid] = b_ih[512 + tid];
        bhn_l[tid] = b_hh[512 + tid];
        bq1_l[tid] = b_q1[tid];
        lng_l[tid] = g_ln[tid];
        lnb_l[tid] = beta_ln[tid];
    } else if (tid < 384) {
        bq2_l[tid - 256] = b_q2[tid - 256];
    }
    for (int i = tid; i < RPB * L_; i += NTH) {
        int r = i >> 8, tt = i & 255;
        act8_l[tt][r] = (unsigned char)actions[(row0 + r) * L_ + tt];
    }
    for (int i = tid; i < NA_ * HD_; i += NTH)
        actp_l[i >> 8][i & 255] = actp[i];
    for (int i = tid; i < 16384; i += NTH)
        ((int*)wq1w_l)[i] = ((const int*)(wpk + OFF_WQ1W))[i];
    for (int i = tid; i < 4096; i += NTH) h8a[i] = 0;
    for (int i = tid; i < 1024; i += NTH) zF[i] = 0;
    f32x4 hreg = zero4;

    unsigned obs_off = (unsigned)((row0 + w) * L_) * (WD_ * 4u) + (unsigned)lane * 8u;
    unsigned nz_off  = (unsigned)((row0 + w) * L_) * (SD_ * 4u) + (unsigned)lane * 4u;
    unsigned ho_off  = (unsigned)((row0 + lrow) * L_) * (OUT_ * 4u) + (unsigned)c0 * 4u;
    unsigned zo_off  = (unsigned)((row0 + w) * L_) * (OUT_ * 4u);
    __syncthreads();   // drains prologue VMEM; ledger starts at 0

    NB n0, n1, n2, n3;
    fp8x8 db0, db1, db2, db3, db4, db5, db6, db7;
    bf16x8 eb0, eb1, eb2, eb3;
    bf16x8 wzb0, wzb1;
    f32x2 obsv, obsv_n;
    float nzv, nzv_n;

    // BOOTSTRAP: [obs nz Wz(2) K0-3(8)] = 12; VMW(10) -> obs,nz; st4 -> 14
    obsv = gload2f(obs, obs_off);
    nzv  = gload1f(noise, nz_off);
    wzb0 = gload<0>   (sbwz, voff16);
    wzb1 = gload<1024>(sbwz, voff16);
    issueN<0>(n0, s8ni, s8nh, voff8);
    issueN<1>(n1, s8ni, s8nh, voff8);
    issueN<2>(n2, s8ni, s8nh, voff8);
    issueN<3>(n3, s8ni, s8nh, voff8);
    VMW(10);
    {
        unsigned doff = (unsigned)tid * 16u;
        gstore4f(dscr, doff, zero4);
        gstore4f(dscr, doff + 16384u, zero4);
        gstore4f(dscr, doff + 32768u, zero4);
        gstore4f(dscr, doff + 49152u, zero4);
    }

    for (int t = 0; t < L_; ++t) {
        const char* h8c = (t & 1) ? h8b : h8a;   // read in B
        char*       h8n = (t & 1) ? h8a : h8b;   // written in C, read in D

        // ---- Phase A: xpre = z@Wz + actp[act]; LN partials; obsF stage ------
        f32x4 xp;
        {
            VMW(12);   // Wz pair complete ([K0-3(8) st4]=12 behind)
            f32x4 a = zero4;
            a = mfma16(wzb0, *(const bf16x8*)&zF[foff], a);
            a = mfma16(wzb1, *(const bf16x8*)&zF[512 + foff], a);
            int act = act8_l[t][lrow];
            xp = a + *(const f32x4*)&actp_l[act][c0];
            float s  = xp[0] + xp[1] + xp[2] + xp[3];
            float ss = xp[0]*xp[0] + xp[1]*xp[1] + xp[2]*xp[2] + xp[3]*xp[3];
            s  += __shfl_xor(s, 16, 64);  s  += __shfl_xor(s, 32, 64);
            ss += __shfl_xor(ss, 16, 64); ss += __shfl_xor(ss, 32, 64);
            if (lgrp == 0) { ps_s[lrow][w] = s; ps_ss[lrow][w] = ss; }
            // obs -> obsF bf16 (wave w = row w; 2 shorts per lane)
            int oc = lane * 2;
            *(unsigned*)&obsF[(oc >> 5) * 512 + (w + 16 * ((oc >> 3) & 3)) * 8 + (oc & 7)]
                = cvtpk(obsv[0], obsv[1]);
        }
        BAR();   // (1)

        // ---- LN finish + xF8 (fp8) -------------------------------------------
        {
            float s  = ps_s [lrow][lgrp] + ps_s [lrow][lgrp + 4]
                     + ps_s [lrow][lgrp + 8] + ps_s [lrow][lgrp + 12];
            float ss = ps_ss[lrow][lgrp] + ps_ss[lrow][lgrp + 4]
                     + ps_ss[lrow][lgrp + 8] + ps_ss[lrow][lgrp + 12];
            s  += __shfl_xor(s, 16, 64);  s  += __shfl_xor(s, 32, 64);
            ss += __shfl_xor(ss, 16, 64); ss += __shfl_xor(ss, 32, 64);
            float mean = s * (1.f / 256.f);
            float rstd = rsqrtf(ss * (1.f / 256.f) - mean * mean + 1e-5f);
            f32x4 g  = *(const f32x4*)&lng_l[c0];
            f32x4 bb = *(const f32x4*)&lnb_l[c0];
            float r0 = fmaxf((xp[0] - mean) * rstd * g[0] + bb[0], 0.f);
            float r1 = fmaxf((xp[1] - mean) * rstd * g[1] + bb[1], 0.f);
            float r2 = fmaxf((xp[2] - mean) * rstd * g[2] + bb[2], 0.f);
            float r3 = fmaxf((xp[3] - mean) * rstd * g[3] + bb[3], 0.f);
            *(int*)&xF8[fwb] = pk4fp8(r0, r1, r2, r3);
        }
        BAR();   // (2)

        // ---- Phase B: GRU (resident r/u + streamed n), deep pipeline ---------
        f32x4 ar = zero4, au = zero4, aI = zero4, aH = zero4;
#define SLOT(KT, NBUF) { \
        fp8x8 x8 = *(const fp8x8*)&xF8[(KT) * 512 + b8off]; \
        fp8x8 h8 = *(const fp8x8*)&h8c[(KT) * 512 + b8off]; \
        ar = mfma8(Rih[KT], x8, ar); ar = mfma8(Rhh[KT], h8, ar); \
        au = mfma8(Uih[KT], x8, au); au = mfma8(Uhh[KT], h8, au); \
        aI = mfma8(NBUF.ni, x8, aI); aH = mfma8(NBUF.nh, h8, aH); }

        VMW(10); SLOT(0, n0) issueN<4>(n0, s8ni, s8nh, voff8);
        VMW(10); SLOT(1, n1) issueN<5>(n1, s8ni, s8nh, voff8);
        VMW(10); SLOT(2, n2) issueN<6>(n2, s8ni, s8nh, voff8);
        VMW(10); SLOT(3, n3) issueN<7>(n3, s8ni, s8nh, voff8);
        VMW(6);  SLOT(4, n0)
        db0 = gload8<0>   (s8q1h, voff8);
        db1 = gload8<512> (s8q1h, voff8);
        db2 = gload8<1024>(s8q1h, voff8);
        db3 = gload8<1536>(s8q1h, voff8);
        VMW(8);  SLOT(5, n1)
        db4 = gload8<2048>(s8q1h, voff8);
        db5 = gload8<2560>(s8q1h, voff8);
        db6 = gload8<3072>(s8q1h, voff8);
        db7 = gload8<3584>(s8q1h, voff8);
        VMW(10); SLOT(6, n2)
        VMW(8);  SLOT(7, n3)
        eb0 = gload<0>   (sbq2, voff16);
        eb1 = gload<1024>(sbq2, voff16);
        eb2 = gload<2048>(sbq2, voff16);
        eb3 = gload<3072>(sbq2, voff16);
        {
            unsigned onext = obs_off + ((t < L_ - 1) ? (WD_ * 4u) : 0u);
            unsigned nnext = nz_off  + ((t < L_ - 1) ? (SD_ * 4u) : 0u);
            obsv_n = gload2f(obs, onext);
            nzv_n  = gload1f(noise, nnext);
            obs_off = onext; nz_off = nnext;
        }
#undef SLOT
        // (no barrier: C writes the other h buffer)

        // ---- Phase C: gates (VALU), write h8n --------------------------------
        {
            f32x4 bsr = *(const f32x4*)&bsr_l[c0];
            f32x4 bsu = *(const f32x4*)&bsu_l[c0];
            f32x4 bin = *(const f32x4*)&bin_l[c0];
            f32x4 bhn = *(const f32x4*)&bhn_l[c0];
            f32x4 hv;
            #pragma unroll
            for (int j = 0; j < 4; ++j) {
                float rr = sigmoidf_(ar[j] + bsr[j]);
                float uu = sigmoidf_(au[j] + bsu[j]);
                float nn = tanhf_(aI[j] + bin[j] + rr * (aH[j] + bhn[j]));
                hv[j] = (1.f - uu) * nn + uu * hreg[j];
            }
            hreg = hv;
            *(int*)&h8n[fwb] = pk4fp8(hv[0], hv[1], hv[2], hv[3]);
        }
        BAR();   // (4)

        // ---- Phase D: q1 = relu(h@Wq1h[fp8] + obs@Wq1w[bf16 LDS] + b_q1) -----
        {
            f32x4 aq = zero4;
            fp8x8 t0 = *(const fp8x8*)&h8n[0 * 512 + b8off];
            fp8x8 t1 = *(const fp8x8*)&h8n[1 * 512 + b8off];
            fp8x8 t2 = *(const fp8x8*)&h8n[2 * 512 + b8off];
            fp8x8 t3 = *(const fp8x8*)&h8n[3 * 512 + b8off];
            VMW(10);   // db0-3 ready (behind: db4-7(4)+eb4+obs+nz = 10)
            aq = mfma8(db0, t0, aq); aq = mfma8(db1, t1, aq);
            aq = mfma8(db2, t2, aq); aq = mfma8(db3, t3, aq);
            fp8x8 t4 = *(const fp8x8*)&h8n[4 * 512 + b8off];
            fp8x8 t5 = *(const fp8x8*)&h8n[5 * 512 + b8off];
            fp8x8 t6 = *(const fp8x8*)&h8n[6 * 512 + b8off];
            fp8x8 t7 = *(const fp8x8*)&h8n[7 * 512 + b8off];
            VMW(6);    // db4-7 ready (behind: eb4+obs+nz = 6)
            aq = mfma8(db4, t4, aq); aq = mfma8(db5, t5, aq);
            aq = mfma8(db6, t6, aq); aq = mfma8(db7, t7, aq);
            // issue NEXT step stream: Wz'(2), K0-3'(8)
            wzb0 = gload<0>   (sbwz, voff16);
            wzb1 = gload<1024>(sbwz, voff16);
            issueN<0>(n0, s8ni, s8nh, voff8);
            issueN<1>(n1, s8ni, s8nh, voff8);
            issueN<2>(n2, s8ni, s8nh, voff8);
            issueN<3>(n3, s8ni, s8nh, voff8);
            // obs part: Wq1w from LDS (pairwise load/use to cap live regs)
            #pragma unroll
            for (int kk = 0; kk < 4; ++kk) {
                bf16x8 ow = *(const bf16x8*)&wq1w_l[(wu * 4 + kk) * 512 + foff];
                bf16x8 of = *(const bf16x8*)&obsF[kk * 512 + foff];
                aq = mfma16(ow, of, aq);
            }
            f32x4 bq = *(const f32x4*)&bq1_l[c0];
            u32x2 qb;
            qb[0] = cvtpk(fmaxf(aq[0] + bq[0], 0.f), fmaxf(aq[1] + bq[1], 0.f));
            qb[1] = cvtpk(fmaxf(aq[2] + bq[2], 0.f), fmaxf(aq[3] + bq[3], 0.f));
            *(u32x2*)&q1F[fwb] = qb;
        }
        BAR();   // (5)

        // ---- Phase E: q2 partials (streamed bf16 eb) -------------------------
        {
            f32x4 a = zero4;
            VMW(12);   // eb done (behind: obs' nz' Wz'2 K0-3'8 = 12)
            bf16x8 q0 = *(const bf16x8*)&q1F[(khalf * 4 + 0) * 512 + foff];
            bf16x8 q1 = *(const bf16x8*)&q1F[(khalf * 4 + 1) * 512 + foff];
            bf16x8 q2 = *(const bf16x8*)&q1F[(khalf * 4 + 2) * 512 + foff];
            bf16x8 q3 = *(const bf16x8*)&q1F[(khalf * 4 + 3) * 512 + foff];
            a = mfma16(eb0, q0, a); a = mfma16(eb1, q1, a);
            a = mfma16(eb2, q2, a); a = mfma16(eb3, q3, a);
            *(f32x4*)&q2p[khalf][lrow][(wu & 7) * 16 + lgrp * 4] = a;
        }
        BAR();   // (6)

        // ---- Phase F: z sample; zF; counted out-stores -----------------------
        {
            int n = lane;   // wave w = row w
            VMW(10);        // obs',nz' done (behind: Wz'2 K0-3'8 = 10)
            float qm = q2p[0][w][n]      + q2p[1][w][n]      + bq2_l[n];
            float ql = q2p[0][w][64 + n] + q2p[1][w][64 + n] + bq2_l[64 + n];
            float qs = softplusf_(ql) + 0.1f;
            float zv = qm + qs * nzv;
            zF[(n >> 5) * 512 + (w + 16 * ((n >> 3) & 3)) * 8 + (n & 7)] = f2bf(zv);
            unsigned zo = zo_off;
            gstore4f(out, ho_off, hreg);
            gstore1f(out, zo + (256 + n) * 4u, zv);
            gstore1f(out, zo + (448 + n) * 4u, qm);
            gstore1f(out, zo + (512 + n) * 4u, qs);
            obsv = obsv_n;
            nzv  = nzv_n;
        }
        BAR();   // (7)
        ho_off += OUT_ * 4u;
        zo_off += OUT_ * 4u;
    }
    asm volatile("s_waitcnt vmcnt(0)" ::: "memory");
}

// ---------------------------------------------------------------------------
__launch_bounds__(256, 2)
__global__ void prior_kernel(const float* __restrict__ b_p1, const float* __restrict__ b_p2,
                             const short* __restrict__ wpk, float* __restrict__ out) {
    const short* wp1 = wpk + OFF_WP1;
    const short* wp2 = wpk + OFF_WP2;
    __shared__ __align__(16) short p1b[4][16][264];
    const int tid = threadIdx.x, wid = tid >> 6, lane = tid & 63;
    const int lrow = lane & 15, lgrp = lane >> 4;
    const size_t rbase = (size_t)blockIdx.x * 64 + wid * 16;
    const f32x4 zero4 = {0.f, 0.f, 0.f, 0.f};

    f32x4 acc[16];
    #pragma unroll
    for (int nt = 0; nt < 16; ++nt) acc[nt] = zero4;
    for (int kt = 0; kt < 8; ++kt) {
        const f32x4* hp = (const f32x4*)&out[(rbase + lrow) * OUT_ + kt * 32 + lgrp * 8];
        f32x4 h0 = hp[0], h1 = hp[1];
        bf16x8 a;
        a[0] = f2bf(h0[0]); a[1] = f2bf(h0[1]); a[2] = f2bf(h0[2]); a[3] = f2bf(h0[3]);
        a[4] = f2bf(h1[0]); a[5] = f2bf(h1[1]); a[6] = f2bf(h1[2]); a[7] = f2bf(h1[3]);
        #pragma unroll
        for (int nt = 0; nt < 16; ++nt) {
            bf16x8 b = *(const bf16x8*)&wp1[(nt * 8 + kt) * 512 + lane * 8];
            acc[nt] = mfma16(a, b, acc[nt]);
        }
    }
    #pragma unroll
    for (int nt = 0; nt < 16; ++nt) {
        int colb = nt * 16 + lrow;
        #pragma unroll
        for (int j = 0; j < 4; ++j)
            p1b[wid][lgrp * 4 + j][colb] = f2bf(fmaxf(acc[nt][j] + b_p1[colb], 0.f));
    }
    __syncthreads();

    f32x4 acc2[8];
    #pragma unroll
    for (int nt = 0; nt < 8; ++nt) acc2[nt] = zero4;
    for (int kt = 0; kt < 8; ++kt) {
        bf16x8 a = *(const bf16x8*)&p1b[wid][lrow][kt * 32 + lgrp * 8];
        #pragma unroll
        for (int nt = 0; nt < 8; ++nt) {
            bf16x8 b = *(const bf16x8*)&wp2[(nt * 8 + kt) * 512 + lane * 8];
            acc2[nt] = mfma16(a, b, acc2[nt]);
        }
    }
    #pragma unroll
    for (int nt = 0; nt < 8; ++nt) {
        #pragma unroll
        for (int j = 0; j < 4; ++j) {
            size_t rw = rbase + lgrp * 4 + j;
            int col = nt * 16 + lrow;
            float v = acc2[nt][j] + b_p2[col];
            if (col < 64) out[rw * OUT_ + 320 + col] = v;
            else          out[rw * OUT_ + 384 + (col - 64)] = softplusf_(v) + 0.1f;
        }
    }
}

// ---------------------------------------------------------------------------
extern "C" void kernel_launch(void* const* d_in, const int* in_sizes, int n_in,
                              void* d_out, int out_size, void* d_ws, size_t ws_size,
                              hipStream_t stream) {
    const int*   actions = (const int*)  d_in[0];
    const float* obs     = (const float*)d_in[1];
    const float* noise   = (const float*)d_in[2];
    const float* emb     = (const float*)d_in[3];
    const float* w_in    = (const float*)d_in[4];
    const float* b_in    = (const float*)d_in[5];
    const float* g_ln    = (const float*)d_in[6];
    const float* beta_ln = (const float*)d_in[7];
    const float* w_ih    = (const float*)d_in[8];
    const float* b_ih    = (const float*)d_in[9];
    const float* w_hh    = (const float*)d_in[10];
    const float* b_hh    = (const float*)d_in[11];
    const float* w_p1    = (const float*)d_in[12];
    const float* b_p1    = (const float*)d_in[13];
    const float* w_p2    = (const float*)d_in[14];
    const float* b_p2    = (const float*)d_in[15];
    const float* w_q1    = (const float*)d_in[16];
    const float* b_q1    = (const float*)d_in[17];
    const float* w_q2    = (const float*)d_in[18];
    const float* b_q2    = (const float*)d_in[19];

    short* wpk  = (short*)d_ws;
    float* actp = (float*)((char*)d_ws + OFF_ACTP_BYTES);
    float* dscr = (float*)((char*)d_ws + OFF_DSCR_BYTES);
    char*  w8   = (char*) d_ws + OFF_W8_BYTES;
    float* out  = (float*)d_out;

    auto packLaunch = [&](const float* W, int off, int KT, int rowOff, int srcN, int total) {
        pack_w_kernel<<<(total + 255) / 256, 256, 0, stream>>>(W, wpk + off, KT, rowOff, srcN, total);
    };
    packLaunch(w_in, OFF_WZ,    2, 0,   256, 64 * 256);
    packLaunch(w_q1, OFF_WQ1W,  4, 256, 256, 128 * 256);
    packLaunch(w_q2, OFF_WQ2,   8, 0,   128, 256 * 128);
    packLaunch(w_p1, OFF_WP1,   8, 0,   256, 256 * 256);
    packLaunch(w_p2, OFF_WP2,   8, 0,   128, 256 * 128);

    auto pack8 = [&](const float* W, int dstOff, int colOff, int srcN) {
        pack_f8_kernel<<<256, 256, 0, stream>>>(W, w8 + dstOff, 8, 0, colOff, srcN, 65536);
    };
    pack8(w_ih, W8_IHR, 0,   768);
    pack8(w_ih, W8_IHU, 256, 768);
    pack8(w_ih, W8_IHN, 512, 768);
    pack8(w_hh, W8_HHR, 0,   768);
    pack8(w_hh, W8_HHU, 256, 768);
    pack8(w_hh, W8_HHN, 512, 768);
    pack8(w_q1, W8_Q1H, 0,   256);
    act_proj_kernel<<<NA_, 256, 0, stream>>>(emb, w_in, b_in, actp);

    scan_kernel<<<B_ / RPB, NTH, 0, stream>>>(actions, obs, noise, b_ih, b_hh,
                                              g_ln, beta_ln, b_q1, b_q2, wpk, w8, actp, dscr, out);
    prior_kernel<<<(B_ * L_) / 64, 256, 0, stream>>>(b_p1, b_p2, wpk, out);
}